// Round 3
// baseline (249.012 us; speedup 1.0000x reference)
//
#include <hip/hip_runtime.h>
#include <hip/hip_bf16.h>

// LossUnsupervised v3 — register-resident B, zero-LDS persistent GEMM.
// prep (32x256): m -> bf16 frag-order (ws) + |m_k|^2 + 1/s1^2.
// fused_main (256x256, 1 wave/SIMD): each wave holds ALL of B (m, bf16,
//   64 frags = 256 VGPR) in registers; streams 256 rows of x (16 chunks
//   of 16) straight from global (read once, prefetched 1 chunk ahead),
//   2-term split-bf16 MFMA, fused normalize + softmax-entropy epilogue.
//   No LDS, no __syncthreads, no inter-wave traffic.
// finalize (1x1024): wavesum reduce (double) + inter-center entropy.

#define N_ROWS 262144

typedef __attribute__((ext_vector_type(8))) short bf16x8;
typedef __attribute__((ext_vector_type(4))) float f32x4;
typedef __attribute__((ext_vector_type(4))) unsigned short u16x4;

__device__ __forceinline__ unsigned short bf16_rne(float x) {
    unsigned int u = __float_as_uint(x);
    u += 0x7FFFu + ((u >> 16) & 1u);
    return (unsigned short)(u >> 16);
}
__device__ __forceinline__ float bf16f(unsigned short h) {
    return __uint_as_float(((unsigned int)h) << 16);
}

__global__ __launch_bounds__(256) void prep(
    const float* __restrict__ m, const float* __restrict__ s1,
    unsigned short* __restrict__ mhi_g, float* __restrict__ mn2_g,
    float* __restrict__ invs_g)
{
    const int t    = threadIdx.x;
    const int lane = t & 63;
    const int k    = blockIdx.x * 8 + (t >> 5);   // center index
    const int f4   = t & 31;                      // float4 within row
    float4 v = reinterpret_cast<const float4*>(m)[k * 32 + f4];
    float pn = v.x*v.x + v.y*v.y + v.z*v.z + v.w*v.w;
    #pragma unroll
    for (int msk = 1; msk <= 16; msk <<= 1) pn += __shfl_xor(pn, msk);
    if ((lane & 31) == 0) {
        mn2_g[k] = pn;
        float sv = s1[k];
        invs_g[k] = 1.0f / (sv * sv);
    }
    const int f0 = f4 << 2;
    const int c = k >> 4, n = k & 15, s = f0 >> 5, blk = (f0 >> 3) & 3, i0 = f0 & 7;
    const int elem = ((c * 4 + s) * 64 + blk * 16 + n) * 8 + i0;
    float xs[4] = {v.x, v.y, v.z, v.w};
    u16x4 hh;
    #pragma unroll
    for (int q = 0; q < 4; ++q) hh[q] = bf16_rne(xs[q]);
    *(u16x4*)(mhi_g + elem) = hh;
}

__global__ __launch_bounds__(256, 1) void fused_main(
    const float* __restrict__ x, const unsigned short* __restrict__ mhi_g,
    const float* __restrict__ mn2_g, const float* __restrict__ invs_g,
    float* __restrict__ wavesum)
{
    const int tid  = threadIdx.x;
    const int lane = tid & 63;
    const int w    = tid >> 6;
    const int rw   = lane & 15;       // x-row within frag / C-col's lane id
    const int blkl = lane >> 4;       // k-block 0..3
    const int gw   = blockIdx.x * 4 + w;   // global wave 0..1023

    // ---- B (all 256 cols x 128 k, bf16) into 256 VGPRs ----
    bf16x8 B[64];
    #pragma unroll
    for (int j = 0; j < 64; ++j)
        B[j] = *(const bf16x8*)(mhi_g + (j * 64 + lane) * 8);

    // per-lane column constants (col = c*16 + rw)
    float bkv[16], isv[16];
    #pragma unroll
    for (int c = 0; c < 16; ++c) {
        bkv[c] = 1.0f + mn2_g[c * 16 + rw];
        isv[c] = invs_g[c * 16 + rw];
    }

    const float* xbase = x + (size_t)(gw * 256 + rw) * 128 + blkl * 8;

    // prefetch chunk 0
    float4 px[8];
    #pragma unroll
    for (int s = 0; s < 4; ++s) {
        px[2*s]   = *(const float4*)(xbase + s * 32);
        px[2*s+1] = *(const float4*)(xbase + s * 32 + 4);
    }

    float ent = 0.0f;

    for (int t = 0; t < 16; ++t) {
        // ---- convert current chunk's A to split bf16, accumulate n2 ----
        bf16x8 ah[4], al[4];
        float n2 = 0.0f;
        #pragma unroll
        for (int s = 0; s < 4; ++s) {
            float xs[8] = {px[2*s].x, px[2*s].y, px[2*s].z, px[2*s].w,
                           px[2*s+1].x, px[2*s+1].y, px[2*s+1].z, px[2*s+1].w};
            #pragma unroll
            for (int q = 0; q < 8; ++q) {
                n2 += xs[q] * xs[q];
                unsigned short h = bf16_rne(xs[q]);
                float r = xs[q] - bf16f(h);
                ah[s][q] = (short)h;
                al[s][q] = (short)bf16_rne(r);
            }
        }
        // ---- issue next chunk's loads (hidden under MFMA+epilogue) ----
        if (t != 15) {
            const float* p = xbase + (size_t)(t + 1) * 16 * 128;
            #pragma unroll
            for (int s = 0; s < 4; ++s) {
                px[2*s]   = *(const float4*)(p + s * 32);
                px[2*s+1] = *(const float4*)(p + s * 32 + 4);
            }
        }
        // ---- MFMA: 16 rows x 256 cols, K=128, 2-term split ----
        f32x4 acc[16];
        #pragma unroll
        for (int c = 0; c < 16; ++c) acc[c] = f32x4{0.f, 0.f, 0.f, 0.f};
        #pragma unroll
        for (int s = 0; s < 4; ++s) {
            #pragma unroll
            for (int c = 0; c < 16; ++c) {
                acc[c] = __builtin_amdgcn_mfma_f32_16x16x32_bf16(al[s], B[c*4+s], acc[c], 0, 0, 0);
                acc[c] = __builtin_amdgcn_mfma_f32_16x16x32_bf16(ah[s], B[c*4+s], acc[c], 0, 0, 0);
            }
        }
        // ---- epilogue: per-row softmax entropy (max = 0; logits <= 0) ----
        n2 += __shfl_xor(n2, 16);
        n2 += __shfl_xor(n2, 32);
        float a2 = 2.0f / fmaxf(sqrtf(n2), 1e-12f);
        #pragma unroll
        for (int reg = 0; reg < 4; ++reg) {
            float ar = __shfl(a2, blkl * 4 + reg);   // scale of C/D row blkl*4+reg
            float S = 0.f, T = 0.f;
            #pragma unroll
            for (int c = 0; c < 16; ++c) {
                float l = fminf(ar * acc[c][reg] - bkv[c], 0.0f) * isv[c];
                float e = __expf(l);
                S += e;
                T += l * e;
            }
            #pragma unroll
            for (int msk = 1; msk <= 8; msk <<= 1) {
                S += __shfl_xor(S, msk);
                T += __shfl_xor(T, msk);
            }
            if (rw == 0) ent += __logf(S) - T / S;   // H = logS - T/S
        }
    }

    ent += __shfl_xor(ent, 16);
    ent += __shfl_xor(ent, 32);
    if (lane == 0) wavesum[gw] = ent;
}

__global__ __launch_bounds__(1024) void finalize(
    const float* __restrict__ wavesum, const float* __restrict__ m,
    const float* __restrict__ s2, float* __restrict__ out)
{
    __shared__ float xmp[8][128];
    __shared__ float xm[128];
    __shared__ double dred[16];
    __shared__ float redS[16], redT[16];
    const int tid  = threadIdx.x;
    const int lane = tid & 63;
    const int w    = tid >> 6;

    // intra partials (1024 floats) in double
    double ds = (double)wavesum[tid];
    #pragma unroll
    for (int msk = 1; msk <= 32; msk <<= 1) ds += __shfl_xor(ds, msk);
    if (lane == 0) dred[w] = ds;

    // mean center: 8 row-groups x 128 cols, coalesced
    {
        const int f = tid & 127, g = tid >> 7;
        const float* mp = m + (size_t)g * 32 * 128 + f;
        float cs = 0.f;
        #pragma unroll 8
        for (int k = 0; k < 32; ++k) cs += mp[(size_t)k * 128];
        xmp[g][f] = cs;
    }
    __syncthreads();
    if (tid < 128) {
        float s = 0.f;
        #pragma unroll
        for (int g = 0; g < 8; ++g) s += xmp[g][tid];
        xm[tid] = s * (1.0f / 256.0f);
    }
    __syncthreads();

    // per-center d2: 256 centers x 4 quarters
    const int k = tid >> 2, q = tid & 3;
    float d2 = 0.f;
    {
        const float4* mr  = (const float4*)(m + (size_t)k * 128) + q * 8;
        const float4* xv4 = (const float4*)xm + q * 8;
        #pragma unroll
        for (int j = 0; j < 8; ++j) {
            float4 mv = mr[j], xv = xv4[j];
            float dx = xv.x - mv.x, dy = xv.y - mv.y,
                  dz = xv.z - mv.z, dw = xv.w - mv.w;
            d2 += dx*dx + dy*dy + dz*dz + dw*dw;
        }
    }
    d2 += __shfl_xor(d2, 1);
    d2 += __shfl_xor(d2, 2);
    // q==0 lanes (every 4th) hold full d2 for center k
    float sv = s2[k];
    float rr = sqrtf(d2) / sv;
    float lg = -(rr * rr);                 // in [-4, 0]: no max pass needed
    float e  = (q == 0) ? __expf(lg) : 0.f;
    float S = e, T = (q == 0) ? lg * e : 0.f;
    #pragma unroll
    for (int msk = 1; msk <= 32; msk <<= 1) {
        S += __shfl_xor(S, msk);
        T += __shfl_xor(T, msk);
    }
    if (lane == 0) { redS[w] = S; redT[w] = T; }
    __syncthreads();
    if (tid == 0) {
        float Sa = 0.f, Ta = 0.f;
        double intra_d = 0.0;
        #pragma unroll
        for (int i = 0; i < 16; ++i) {
            Sa += redS[i]; Ta += redT[i]; intra_d += dred[i];
        }
        float inter = __logf(Sa) - Ta / Sa;
        float intra = (float)(intra_d / (double)N_ROWS);
        out[0] = intra - inter;   // LAMB = 1
        out[1] = intra;
        out[2] = inter;
    }
}

extern "C" void kernel_launch(void* const* d_in, const int* in_sizes, int n_in,
                              void* d_out, int out_size, void* d_ws, size_t ws_size,
                              hipStream_t stream) {
    const float* x  = (const float*)d_in[0];
    const float* m  = (const float*)d_in[1];
    const float* s1 = (const float*)d_in[2];
    const float* s2 = (const float*)d_in[3];
    float* out = (float*)d_out;

    char* ws = (char*)d_ws;
    unsigned short* mhi_g = (unsigned short*)ws;          // 65536 B
    float* mn2_g   = (float*)(ws + 65536);                // 1 KiB
    float* invs_g  = (float*)(ws + 65536 + 1024);         // 1 KiB
    float* wavesum = (float*)(ws + 65536 + 2048);         // 4 KiB (1024 f32)

    prep<<<dim3(32), dim3(256), 0, stream>>>(m, s1, mhi_g, mn2_g, invs_g);
    fused_main<<<dim3(256), dim3(256), 0, stream>>>(x, mhi_g, mn2_g, invs_g, wavesum);
    finalize<<<dim3(1), dim3(1024), 0, stream>>>(wavesum, m, s2, out);
}

// Round 4
// 239.351 us; speedup vs baseline: 1.0404x; 1.0404x over previous
//
#include <hip/hip_runtime.h>
#include <hip/hip_bf16.h>

// LossUnsupervised v4 — register-resident half-B per wave, 2 waves/SIMD.
// prep (32x256): m -> bf16 frag-order (ws) + |m_k|^2 + 1/s1^2.
// fused_main (1024x128): wave pair shares 256 rows (16 chunks of 16);
//   each wave holds 128 of the 256 columns of B in 128 VGPRs, computes
//   partial softmax sums (S,T additive since row-max fixed at 0), writes
//   per-row partials to 4KB LDS; ONE barrier at end, combine, block sum.
//   x streamed once (pair's 2nd read = L2 hit), cvt_pk bf16 split A.
// finalize (1x1024): wavesum reduce (double) + inter-center entropy.

#define N_ROWS 262144

typedef __attribute__((ext_vector_type(8))) short bf16x8;
typedef __attribute__((ext_vector_type(4))) float f32x4;
typedef __attribute__((ext_vector_type(4))) unsigned short u16x4;
typedef __attribute__((ext_vector_type(4))) unsigned int u32x4;

__device__ __forceinline__ unsigned short bf16_rne(float x) {
    unsigned int u = __float_as_uint(x);
    u += 0x7FFFu + ((u >> 16) & 1u);
    return (unsigned short)(u >> 16);
}

__global__ __launch_bounds__(256) void prep(
    const float* __restrict__ m, const float* __restrict__ s1,
    unsigned short* __restrict__ mhi_g, float* __restrict__ mn2_g,
    float* __restrict__ invs_g)
{
    const int t    = threadIdx.x;
    const int lane = t & 63;
    const int k    = blockIdx.x * 8 + (t >> 5);   // center index
    const int f4   = t & 31;                      // float4 within row
    float4 v = reinterpret_cast<const float4*>(m)[k * 32 + f4];
    float pn = v.x*v.x + v.y*v.y + v.z*v.z + v.w*v.w;
    #pragma unroll
    for (int msk = 1; msk <= 16; msk <<= 1) pn += __shfl_xor(pn, msk);
    if ((lane & 31) == 0) {
        mn2_g[k] = pn;
        float sv = s1[k];
        invs_g[k] = 1.0f / (sv * sv);
    }
    const int f0 = f4 << 2;
    const int c = k >> 4, n = k & 15, s = f0 >> 5, blk = (f0 >> 3) & 3, i0 = f0 & 7;
    const int elem = ((c * 4 + s) * 64 + blk * 16 + n) * 8 + i0;
    float xs[4] = {v.x, v.y, v.z, v.w};
    u16x4 hh;
    #pragma unroll
    for (int q = 0; q < 4; ++q) hh[q] = bf16_rne(xs[q]);
    *(u16x4*)(mhi_g + elem) = hh;
}

// convert 8 floats -> split bf16 hi/lo via v_cvt_pk (compiler-generated)
__device__ __forceinline__ void cvt8(float4 a, float4 b, bf16x8& hi, bf16x8& lo,
                                     float& n2a, float& n2b) {
    float xs[8] = {a.x, a.y, a.z, a.w, b.x, b.y, b.z, b.w};
    u32x4 hp, lp;
    #pragma unroll
    for (int p = 0; p < 4; ++p) {
        float e = xs[2*p], o = xs[2*p+1];
        n2a += e * e;
        n2b += o * o;
        __hip_bfloat162 hv = __float22bfloat162_rn(make_float2(e, o));
        unsigned hu = *reinterpret_cast<unsigned*>(&hv);
        float ef = __uint_as_float(hu << 16);
        float of = __uint_as_float(hu & 0xffff0000u);
        __hip_bfloat162 lv = __float22bfloat162_rn(make_float2(e - ef, o - of));
        hp[p] = hu;
        lp[p] = *reinterpret_cast<unsigned*>(&lv);
    }
    hi = *reinterpret_cast<bf16x8*>(&hp);
    lo = *reinterpret_cast<bf16x8*>(&lp);
}

__global__ __launch_bounds__(128, 2) void fused_main(
    const float* __restrict__ x, const unsigned short* __restrict__ mhi_g,
    const float* __restrict__ mn2_g, const float* __restrict__ invs_g,
    float* __restrict__ wavesum)
{
    __shared__ float part[2][16][16][2];   // [wave][chunk][row16][S,T]
    __shared__ float redw[2];

    const int tid  = threadIdx.x;
    const int lane = tid & 63;
    const int w    = tid >> 6;        // wave 0/1: columns [128w, 128w+128)
    const int rw   = lane & 15;       // x-row within frag
    const int blkl = lane >> 4;       // k-block 0..3

    // ---- half-B (128 cols x 128 k, bf16) into 128 VGPRs ----
    bf16x8 B[32];
    #pragma unroll
    for (int jc = 0; jc < 8; ++jc)
        #pragma unroll
        for (int s = 0; s < 4; ++s)
            B[jc*4+s] = *(const bf16x8*)(mhi_g + (((8*w + jc)*4 + s)*64 + lane)*8);

    float bkv[8], isv[8];
    #pragma unroll
    for (int jc = 0; jc < 8; ++jc) {
        int col = (8*w + jc)*16 + rw;
        bkv[jc] = 1.0f + mn2_g[col];
        isv[jc] = invs_g[col];
    }

    const float* xb = x + (size_t)(blockIdx.x*256 + rw)*128 + blkl*8;

    float4 pxA[4], pxB[4];
    #pragma unroll
    for (int s = 0; s < 2; ++s) {
        pxA[2*s]   = *(const float4*)(xb + s*32);
        pxA[2*s+1] = *(const float4*)(xb + s*32 + 4);
    }
    #pragma unroll
    for (int s = 2; s < 4; ++s) {
        pxB[2*(s-2)]   = *(const float4*)(xb + s*32);
        pxB[2*(s-2)+1] = *(const float4*)(xb + s*32 + 4);
    }

    #define MFMA_STEP(s_)                                                        \
        do { _Pragma("unroll")                                                   \
            for (int jc = 0; jc < 8; ++jc) {                                     \
                acc[jc] = __builtin_amdgcn_mfma_f32_16x16x32_bf16(al, B[jc*4+(s_)], acc[jc], 0, 0, 0); \
                acc[jc] = __builtin_amdgcn_mfma_f32_16x16x32_bf16(ah, B[jc*4+(s_)], acc[jc], 0, 0, 0); \
            } } while (0)

    for (int t = 0; t < 16; ++t) {
        const float* xn = xb + (size_t)(t + 1)*2048;   // next chunk base
        f32x4 acc[8];
        #pragma unroll
        for (int jc = 0; jc < 8; ++jc) acc[jc] = f32x4{0.f, 0.f, 0.f, 0.f};

        float n2a = 0.f, n2b = 0.f;
        bf16x8 ah, al;

        cvt8(pxA[0], pxA[1], ah, al, n2a, n2b);
        MFMA_STEP(0);
        cvt8(pxA[2], pxA[3], ah, al, n2a, n2b);
        MFMA_STEP(1);
        if (t < 15) {   // refill pxA (s0,s1 of next chunk)
            #pragma unroll
            for (int s = 0; s < 2; ++s) {
                pxA[2*s]   = *(const float4*)(xn + s*32);
                pxA[2*s+1] = *(const float4*)(xn + s*32 + 4);
            }
        }
        cvt8(pxB[0], pxB[1], ah, al, n2a, n2b);
        MFMA_STEP(2);
        cvt8(pxB[2], pxB[3], ah, al, n2a, n2b);
        MFMA_STEP(3);
        if (t < 15) {   // refill pxB (s2,s3 of next chunk)
            #pragma unroll
            for (int s = 2; s < 4; ++s) {
                pxB[2*(s-2)]   = *(const float4*)(xn + s*32);
                pxB[2*(s-2)+1] = *(const float4*)(xn + s*32 + 4);
            }
        }

        // ---- per-row partial softmax sums over this wave's 128 cols ----
        float n2 = n2a + n2b;
        n2 += __shfl_xor(n2, 16);
        n2 += __shfl_xor(n2, 32);
        float a2 = 2.0f / fmaxf(sqrtf(n2), 1e-12f);
        #pragma unroll
        for (int reg = 0; reg < 4; ++reg) {
            float ar = __shfl(a2, blkl*4 + reg);
            float S0 = 0.f, S1 = 0.f, T0 = 0.f, T1 = 0.f;
            #pragma unroll
            for (int jc = 0; jc < 8; ++jc) {
                float l = fminf(ar * acc[jc][reg] - bkv[jc], 0.0f) * isv[jc];
                float e = __expf(l);
                if (jc & 1) { S1 += e; T1 += l * e; }
                else        { S0 += e; T0 += l * e; }
            }
            float S = S0 + S1, T = T0 + T1;
            #pragma unroll
            for (int msk = 1; msk <= 8; msk <<= 1) {
                S += __shfl_xor(S, msk);
                T += __shfl_xor(T, msk);
            }
            if (rw == 0) {
                float2 st = make_float2(S, T);
                *(float2*)&part[w][t][blkl*4 + reg][0] = st;
            }
        }
    }
    #undef MFMA_STEP

    __syncthreads();

    // ---- combine halves: each thread finishes 2 rows ----
    float entloc = 0.f;
    #pragma unroll
    for (int r2 = 0; r2 < 2; ++r2) {
        int r = tid*2 + r2, c = r >> 4, r16 = r & 15;
        float S = part[0][c][r16][0] + part[1][c][r16][0];
        float T = part[0][c][r16][1] + part[1][c][r16][1];
        entloc += __logf(S) - T / S;
    }
    #pragma unroll
    for (int msk = 1; msk <= 32; msk <<= 1) entloc += __shfl_xor(entloc, msk);
    if (lane == 0) redw[w] = entloc;
    __syncthreads();
    if (tid == 0) wavesum[blockIdx.x] = redw[0] + redw[1];
}

__global__ __launch_bounds__(1024) void finalize(
    const float* __restrict__ wavesum, const float* __restrict__ m,
    const float* __restrict__ s2, float* __restrict__ out)
{
    __shared__ float xmp[8][128];
    __shared__ float xm[128];
    __shared__ double dred[16];
    __shared__ float redS[16], redT[16];
    const int tid  = threadIdx.x;
    const int lane = tid & 63;
    const int w    = tid >> 6;

    double ds = (double)wavesum[tid];
    #pragma unroll
    for (int msk = 1; msk <= 32; msk <<= 1) ds += __shfl_xor(ds, msk);
    if (lane == 0) dred[w] = ds;

    {
        const int f = tid & 127, g = tid >> 7;
        const float* mp = m + (size_t)g * 32 * 128 + f;
        float cs = 0.f;
        #pragma unroll 8
        for (int k = 0; k < 32; ++k) cs += mp[(size_t)k * 128];
        xmp[g][f] = cs;
    }
    __syncthreads();
    if (tid < 128) {
        float s = 0.f;
        #pragma unroll
        for (int g = 0; g < 8; ++g) s += xmp[g][tid];
        xm[tid] = s * (1.0f / 256.0f);
    }
    __syncthreads();

    const int k = tid >> 2, q = tid & 3;
    float d2 = 0.f;
    {
        const float4* mr  = (const float4*)(m + (size_t)k * 128) + q * 8;
        const float4* xv4 = (const float4*)xm + q * 8;
        #pragma unroll
        for (int j = 0; j < 8; ++j) {
            float4 mv = mr[j], xv = xv4[j];
            float dx = xv.x - mv.x, dy = xv.y - mv.y,
                  dz = xv.z - mv.z, dw = xv.w - mv.w;
            d2 += dx*dx + dy*dy + dz*dz + dw*dw;
        }
    }
    d2 += __shfl_xor(d2, 1);
    d2 += __shfl_xor(d2, 2);
    float sv = s2[k];
    float rr = sqrtf(d2) / sv;
    float lg = -(rr * rr);
    float e  = (q == 0) ? __expf(lg) : 0.f;
    float S = e, T = (q == 0) ? lg * e : 0.f;
    #pragma unroll
    for (int msk = 1; msk <= 32; msk <<= 1) {
        S += __shfl_xor(S, msk);
        T += __shfl_xor(T, msk);
    }
    if (lane == 0) { redS[w] = S; redT[w] = T; }
    __syncthreads();
    if (tid == 0) {
        float Sa = 0.f, Ta = 0.f;
        double intra_d = 0.0;
        #pragma unroll
        for (int i = 0; i < 16; ++i) {
            Sa += redS[i]; Ta += redT[i]; intra_d += dred[i];
        }
        float inter = __logf(Sa) - Ta / Sa;
        float intra = (float)(intra_d / (double)N_ROWS);
        out[0] = intra - inter;   // LAMB = 1
        out[1] = intra;
        out[2] = inter;
    }
}

extern "C" void kernel_launch(void* const* d_in, const int* in_sizes, int n_in,
                              void* d_out, int out_size, void* d_ws, size_t ws_size,
                              hipStream_t stream) {
    const float* x  = (const float*)d_in[0];
    const float* m  = (const float*)d_in[1];
    const float* s1 = (const float*)d_in[2];
    const float* s2 = (const float*)d_in[3];
    float* out = (float*)d_out;

    char* ws = (char*)d_ws;
    unsigned short* mhi_g = (unsigned short*)ws;          // 65536 B
    float* mn2_g   = (float*)(ws + 65536);                // 1 KiB
    float* invs_g  = (float*)(ws + 65536 + 1024);         // 1 KiB
    float* wavesum = (float*)(ws + 65536 + 2048);         // 4 KiB (1024 f32)

    prep<<<dim3(32), dim3(256), 0, stream>>>(m, s1, mhi_g, mn2_g, invs_g);
    fused_main<<<dim3(1024), dim3(128), 0, stream>>>(x, mhi_g, mn2_g, invs_g, wavesum);
    finalize<<<dim3(1), dim3(1024), 0, stream>>>(wavesum, m, s2, out);
}

// Round 5
// 231.669 us; speedup vs baseline: 1.0749x; 1.0332x over previous
//
#include <hip/hip_runtime.h>
#include <hip/hip_bf16.h>

// LossUnsupervised v5 — swapped-operand MFMA (m = A, x = B), quarter-B/wave.
// prep (32x256): m' = m/s1^2 -> bf16 A-frag order (ws); p2 = (1+|m|^2)/s1^2.
// fused_main (2048x256, 4 waves): all 4 waves share the block's 128 rows
//   (8 chunks of 16); wave w holds centers [64w,64w+64) of m' in 64 VGPRs.
//   D = m'.x^T puts a full row's logits lane-local: softmax partials (S,T)
//   are in-register sums + 2 shfl_xor (max fixed at 0). Partials -> 4KB LDS,
//   ONE barrier, combine, block sum. x read once (waves share via L1).
// finalize (1x1024): blocksum reduce (double) + inter-center entropy.

#define N_ROWS 262144

typedef __attribute__((ext_vector_type(8))) short bf16x8;
typedef __attribute__((ext_vector_type(4))) float f32x4;
typedef __attribute__((ext_vector_type(4))) unsigned short u16x4;

__device__ __forceinline__ unsigned short bf16_rne(float x) {
    unsigned int u = __float_as_uint(x);
    u += 0x7FFFu + ((u >> 16) & 1u);
    return (unsigned short)(u >> 16);
}

// 8 floats -> split bf16 hi/lo (cvt_pk), n2 += sum of squares
__device__ __forceinline__ void cvt8(float4 a, float4 b, bf16x8& hi, bf16x8& lo,
                                     float& n2) {
    float xs[8] = {a.x, a.y, a.z, a.w, b.x, b.y, b.z, b.w};
    unsigned hp[4], lp[4];
    #pragma unroll
    for (int p = 0; p < 4; ++p) {
        float e = xs[2*p], o = xs[2*p+1];
        n2 = __builtin_fmaf(e, e, n2);
        n2 = __builtin_fmaf(o, o, n2);
        __hip_bfloat162 hv = __float22bfloat162_rn(make_float2(e, o));
        unsigned hu = *reinterpret_cast<unsigned*>(&hv);
        float ef = __uint_as_float(hu << 16);
        float of = __uint_as_float(hu & 0xffff0000u);
        __hip_bfloat162 lv = __float22bfloat162_rn(make_float2(e - ef, o - of));
        hp[p] = hu;
        lp[p] = *reinterpret_cast<unsigned*>(&lv);
    }
    hi = *reinterpret_cast<bf16x8*>(hp);
    lo = *reinterpret_cast<bf16x8*>(lp);
}

__global__ __launch_bounds__(256) void prep(
    const float* __restrict__ m, const float* __restrict__ s1,
    unsigned short* __restrict__ mhi_g, float* __restrict__ p2_g)
{
    const int t    = threadIdx.x;
    const int lane = t & 63;
    const int k    = blockIdx.x * 8 + (t >> 5);   // center index
    const int f4   = t & 31;                      // float4 within row
    float4 v = reinterpret_cast<const float4*>(m)[k * 32 + f4];
    float pn = v.x*v.x + v.y*v.y + v.z*v.z + v.w*v.w;
    #pragma unroll
    for (int msk = 1; msk <= 16; msk <<= 1) pn += __shfl_xor(pn, msk);
    float sv  = s1[k];
    float isv = 1.0f / (sv * sv);
    if ((lane & 31) == 0) p2_g[k] = (1.0f + pn) * isv;   // (1+|m|^2)/s^2
    const int f0 = f4 << 2;
    const int c = k >> 4, n = k & 15, s = f0 >> 5, blk = (f0 >> 3) & 3, i0 = f0 & 7;
    const int elem = ((c * 4 + s) * 64 + blk * 16 + n) * 8 + i0;
    float xs[4] = {v.x * isv, v.y * isv, v.z * isv, v.w * isv};  // m' = m/s^2
    u16x4 hh;
    #pragma unroll
    for (int q = 0; q < 4; ++q) hh[q] = bf16_rne(xs[q]);
    *(u16x4*)(mhi_g + elem) = hh;
}

__global__ __launch_bounds__(256, 3) void fused_main(
    const float* __restrict__ x, const unsigned short* __restrict__ mhi_g,
    const float* __restrict__ p2_g, float* __restrict__ blocksum)
{
    __shared__ float p2s[256];
    __shared__ float part[8][16][4][2];   // [chunk][row16][wave][S,T]
    __shared__ float entred[4];

    const int tid  = threadIdx.x;
    const int lane = tid & 63;
    const int w    = tid >> 6;        // wave 0..3: centers [64w, 64w+64)
    const int rw   = lane & 15;       // x-row within chunk (C col)
    const int blkl = lane >> 4;       // k-block / C row-group

    p2s[tid] = p2_g[tid];

    // quarter-B: 4 center-tiles x 4 k-steps, 64 VGPR, stationary
    bf16x8 MB[16];
    #pragma unroll
    for (int tt = 0; tt < 4; ++tt)
        #pragma unroll
        for (int s = 0; s < 4; ++s)
            MB[tt*4+s] = *(const bf16x8*)(mhi_g + (((4*w + tt)*4 + s)*64 + lane)*8);

    __syncthreads();   // p2s ready

    const float* xb = x + (size_t)(blockIdx.x * 128 + rw) * 128 + blkl * 8;

    // 3-deep circular prefetch over flattened ksteps g = t*4 + s
    float4 PA[3], PB[3];
    #pragma unroll
    for (int g = 0; g < 3; ++g) {
        PA[g] = *(const float4*)(xb + g * 32);
        PB[g] = *(const float4*)(xb + g * 32 + 4);
    }

    f32x4 acc[4];
    float n2 = 0.0f;

    #pragma unroll
    for (int g = 0; g < 32; ++g) {
        const int s = g & 3;             // k-step within chunk
        const int slot = g % 3;
        if (s == 0) {
            #pragma unroll
            for (int tt = 0; tt < 4; ++tt) acc[tt] = f32x4{0.f, 0.f, 0.f, 0.f};
            n2 = 0.0f;
        }
        bf16x8 ah, al;
        cvt8(PA[slot], PB[slot], ah, al, n2);
        if (g + 3 < 32) {   // refill this slot with kstep g+3
            const int g2 = g + 3;
            const float* p = xb + (size_t)(g2 >> 2) * 2048 + (g2 & 3) * 32;
            PA[slot] = *(const float4*)(p);
            PB[slot] = *(const float4*)(p + 4);
        }
        #pragma unroll
        for (int tt = 0; tt < 4; ++tt) {
            acc[tt] = __builtin_amdgcn_mfma_f32_16x16x32_bf16(MB[tt*4+s], al, acc[tt], 0, 0, 0);
            acc[tt] = __builtin_amdgcn_mfma_f32_16x16x32_bf16(MB[tt*4+s], ah, acc[tt], 0, 0, 0);
        }
        if (s == 3) {
            // ---- chunk epilogue: lane-local softmax partials ----
            const int t = g >> 2;
            float nn = n2;
            nn += __shfl_xor(nn, 16);
            nn += __shfl_xor(nn, 32);        // all 4 lanes of row rw share nn
            float ar = 2.0f / fmaxf(sqrtf(nn), 1e-12f);
            float S = 0.f, T = 0.f;
            #pragma unroll
            for (int tt = 0; tt < 4; ++tt) {
                f32x4 p2v = *(const f32x4*)&p2s[(4*w + tt)*16 + blkl*4];
                #pragma unroll
                for (int r = 0; r < 4; ++r) {
                    float l = fminf(__builtin_fmaf(ar, acc[tt][r], -p2v[r]), 0.0f);
                    float e = __expf(l);
                    S += e;
                    T = __builtin_fmaf(l, e, T);
                }
            }
            S += __shfl_xor(S, 16);  T += __shfl_xor(T, 16);
            S += __shfl_xor(S, 32);  T += __shfl_xor(T, 32);
            if (blkl == 0)
                *(float2*)&part[t][rw][w][0] = make_float2(S, T);
        }
    }

    __syncthreads();

    // ---- combine wave partials: thread r finishes row r (r < 128) ----
    float entl = 0.0f;
    if (tid < 128) {
        const int c = tid >> 4, r16 = tid & 15;
        float S = part[c][r16][0][0] + part[c][r16][1][0]
                + part[c][r16][2][0] + part[c][r16][3][0];
        float T = part[c][r16][0][1] + part[c][r16][1][1]
                + part[c][r16][2][1] + part[c][r16][3][1];
        entl = __logf(S) - T / S;
    }
    #pragma unroll
    for (int msk = 1; msk <= 32; msk <<= 1) entl += __shfl_xor(entl, msk);
    if (lane == 0) entred[w] = entl;
    __syncthreads();
    if (tid == 0)
        blocksum[blockIdx.x] = entred[0] + entred[1] + entred[2] + entred[3];
}

__global__ __launch_bounds__(1024) void finalize(
    const float* __restrict__ blocksum, const float* __restrict__ m,
    const float* __restrict__ s2, float* __restrict__ out)
{
    __shared__ float xmp[8][128];
    __shared__ float xm[128];
    __shared__ double dred[16];
    __shared__ float redS[16], redT[16];
    const int tid  = threadIdx.x;
    const int lane = tid & 63;
    const int w    = tid >> 6;

    // intra partials (2048) in double
    double ds = (double)blocksum[tid] + (double)blocksum[tid + 1024];
    #pragma unroll
    for (int msk = 1; msk <= 32; msk <<= 1) ds += __shfl_xor(ds, msk);
    if (lane == 0) dred[w] = ds;

    // mean center: coalesced column sums
    {
        const int f = tid & 127, g = tid >> 7;
        const float* mp = m + (size_t)g * 32 * 128 + f;
        float cs = 0.f;
        #pragma unroll 8
        for (int k = 0; k < 32; ++k) cs += mp[(size_t)k * 128];
        xmp[g][f] = cs;
    }
    __syncthreads();
    if (tid < 128) {
        float s = 0.f;
        #pragma unroll
        for (int g = 0; g < 8; ++g) s += xmp[g][tid];
        xm[tid] = s * (1.0f / 256.0f);
    }
    __syncthreads();

    // per-center d2 (4 lanes per center)
    const int k = tid >> 2, q = tid & 3;
    float d2 = 0.f;
    {
        const float4* mr  = (const float4*)(m + (size_t)k * 128) + q * 8;
        const float4* xv4 = (const float4*)xm + q * 8;
        #pragma unroll
        for (int j = 0; j < 8; ++j) {
            float4 mv = mr[j], xv = xv4[j];
            float dx = xv.x - mv.x, dy = xv.y - mv.y,
                  dz = xv.z - mv.z, dw = xv.w - mv.w;
            d2 += dx*dx + dy*dy + dz*dz + dw*dw;
        }
    }
    d2 += __shfl_xor(d2, 1);
    d2 += __shfl_xor(d2, 2);
    float sv = s2[k];
    float rr = sqrtf(d2) / sv;
    float lg = -(rr * rr);
    float e  = (q == 0) ? __expf(lg) : 0.f;
    float S = e, T = (q == 0) ? lg * e : 0.f;
    #pragma unroll
    for (int msk = 1; msk <= 32; msk <<= 1) {
        S += __shfl_xor(S, msk);
        T += __shfl_xor(T, msk);
    }
    if (lane == 0) { redS[w] = S; redT[w] = T; }
    __syncthreads();
    if (tid == 0) {
        float Sa = 0.f, Ta = 0.f;
        double intra_d = 0.0;
        #pragma unroll
        for (int i = 0; i < 16; ++i) {
            Sa += redS[i]; Ta += redT[i]; intra_d += dred[i];
        }
        float inter = __logf(Sa) - Ta / Sa;
        float intra = (float)(intra_d / (double)N_ROWS);
        out[0] = intra - inter;   // LAMB = 1
        out[1] = intra;
        out[2] = inter;
    }
}

extern "C" void kernel_launch(void* const* d_in, const int* in_sizes, int n_in,
                              void* d_out, int out_size, void* d_ws, size_t ws_size,
                              hipStream_t stream) {
    const float* x  = (const float*)d_in[0];
    const float* m  = (const float*)d_in[1];
    const float* s1 = (const float*)d_in[2];
    const float* s2 = (const float*)d_in[3];
    float* out = (float*)d_out;

    char* ws = (char*)d_ws;
    unsigned short* mhi_g = (unsigned short*)ws;       // 65536 B
    float* p2_g     = (float*)(ws + 65536);            // 1 KiB
    float* blocksum = (float*)(ws + 65536 + 1024);     // 8 KiB (2048 f32)

    prep<<<dim3(32), dim3(256), 0, stream>>>(m, s1, mhi_g, p2_g);
    fused_main<<<dim3(2048), dim3(256), 0, stream>>>(x, mhi_g, p2_g, blocksum);
    finalize<<<dim3(1), dim3(1024), 0, stream>>>(blocksum, m, s2, out);
}